// Round 1
// baseline (160.122 us; speedup 1.0000x reference)
//
#include <hip/hip_runtime.h>
#include <stdint.h>

#pragma clang fp contract(off)

#define NMS_B 8
#define NMS_N 4096
#define NMS_NW 64       // 64-bit words per suppression row
#define ROIS 256

typedef unsigned long long u64;
typedef unsigned int u32;

__device__ __forceinline__ u64 rdlane_u64(u64 v, int l) {
    u32 lo = (u32)__builtin_amdgcn_readlane((int)(u32)v, l);
    u32 hi = (u32)__builtin_amdgcn_readlane((int)(u32)(v >> 32), l);
    return ((u64)hi << 32) | lo;
}
__device__ __forceinline__ u64 rdfirst_u64(u64 v) {
    u32 lo = (u32)__builtin_amdgcn_readfirstlane((int)(u32)v);
    u32 hi = (u32)__builtin_amdgcn_readfirstlane((int)(u32)(v >> 32));
    return ((u64)hi << 32) | lo;
}
__device__ __forceinline__ int lds_slot(int e) { return e + (e >> 2); }  // 4-way max bank aliasing

// ---------------------------------------------------------------------------
// K1a: local bitonic sort of 2048-element chunks (2 chunks/batch, 16 blocks,
// 512 thr x 4 elems). key = (~score_bits)<<32 | GLOBAL idx; direction bits
// use global e, so the result is bit-identical to the monolithic bitonic
// after its k=2048 stage. 66 of 78 stages run here at 2x merge parallelism.
// (unchanged from previous round)
// ---------------------------------------------------------------------------
__global__ __launch_bounds__(512) void nms_sort_local(
        const float* __restrict__ in, u64* __restrict__ keyb) {
    __shared__ u64 sm[2560];                   // slot(2047)=2558, 20.5 KB
    const int b = blockIdx.y, c = blockIdx.x, t = threadIdx.x;
    const int ebase = c * 2048;
    u64 key[4];

    #pragma unroll
    for (int r = 0; r < 4; ++r) {
        int e = ebase + 4 * t + r;
        float s = in[((size_t)b * NMS_N + e) * 5];
        key[r] = ((u64)(~__float_as_uint(s)) << 32) | (u32)e;
    }

    for (int k = 2; k <= 2048; k <<= 1) {
        int j = k >> 1;
        if (j >= 256) {                        // j = 1024,512,256 via LDS
            #pragma unroll
            for (int r = 0; r < 4; ++r) sm[lds_slot(4 * t + r)] = key[r];
            __syncthreads();
            for (; j >= 256; j >>= 1) {
                for (int el = t; el < 2048; el += 512) {
                    int p = el ^ j;
                    if (p > el) {
                        u64 a = sm[lds_slot(el)], cc = sm[lds_slot(p)];
                        bool up = (((ebase + el) & k) == 0);
                        if ((a > cc) == up) { sm[lds_slot(el)] = cc; sm[lds_slot(p)] = a; }
                    }
                }
                __syncthreads();
            }
            #pragma unroll
            for (int r = 0; r < 4; ++r) key[r] = sm[lds_slot(4 * t + r)];
        }
        for (; j >= 4; j >>= 1) {              // cross-lane via shfl_xor
            int d = j >> 2;
            #pragma unroll
            for (int r = 0; r < 4; ++r) {
                int e = ebase + 4 * t + r;
                u64 mine = key[r];
                u64 part = __shfl_xor(mine, d, 64);
                bool up = ((e & k) == 0);
                bool lower = ((e & j) == 0);
                u64 mn = (mine < part) ? mine : part;
                u64 mx = (mine < part) ? part : mine;
                key[r] = (up == lower) ? mn : mx;
            }
        }
        for (; j >= 1; j >>= 1) {              // j in {2,1}: in-thread
            #pragma unroll
            for (int r = 0; r < 4; ++r) {
                int pr = r | j;
                if (((r & j) == 0) && pr < 4) {
                    int e = ebase + 4 * t + r;
                    bool up = ((e & k) == 0);
                    u64 a = key[r], cc = key[pr];
                    if ((a > cc) == up) { key[r] = cc; key[pr] = a; }
                }
            }
        }
    }

    #pragma unroll
    for (int r = 0; r < 4; ++r)
        keyb[(size_t)b * NMS_N + ebase + 4 * t + r] = key[r];
}

// ---------------------------------------------------------------------------
// K1b: merge stage k=4096 at 2x block parallelism. Key observation: at
// k=4096 every element has (e & 4096)==0, so the whole merge is ascending.
// The j=2048 substage pairs chunk0/chunk1 elementwise -> two blocks compute
// it redundantly from read-only keyb (no inter-block sync), then j<=1024
// stays inside each 2048-half. 16 blocks x 512 thr, 20.5 KB LDS (was
// 8 blocks x 1024 thr, 41 KB). Bit-identical network.
// Epilogue: sorted idx + corners (floor(w/2) exactly per reference) +
// HALF-areas (exact: areas are small even integers).
// ---------------------------------------------------------------------------
__global__ __launch_bounds__(512) void nms_sort_merge(
        const float* __restrict__ in, const u64* __restrict__ keyb,
        u32* __restrict__ sortedIdx, float4* __restrict__ crn,
        float* __restrict__ ha) {
    __shared__ u64 sm[2560];                   // slot(2047)=2558, 20.5 KB
    const int b = blockIdx.y, c = blockIdx.x, t = threadIdx.x;
    const int ebase = c * 2048;
    u64 key[4];

    // j = 2048: cross-chunk compare-exchange, all ascending. c=0 keeps min,
    // c=1 keeps max. Redundant load of partner half (read-only -> race-free).
    #pragma unroll
    for (int r = 0; r < 4; ++r) {
        int el = 4 * t + r;
        u64 mine = keyb[(size_t)b * NMS_N + ebase + el];
        u64 part = keyb[(size_t)b * NMS_N + (ebase ^ 2048) + el];
        u64 mn = mine < part ? mine : part;
        u64 mx = mine < part ? part : mine;
        key[r] = (c == 0) ? mn : mx;
    }

    // j = 1024, 512, 256 via LDS (up==true everywhere at k=4096)
    #pragma unroll
    for (int r = 0; r < 4; ++r) sm[lds_slot(4 * t + r)] = key[r];
    __syncthreads();
    for (int j = 1024; j >= 256; j >>= 1) {
        for (int el = t; el < 2048; el += 512) {
            int p = el ^ j;
            if (p > el) {
                u64 a = sm[lds_slot(el)], cc = sm[lds_slot(p)];
                if (a > cc) { sm[lds_slot(el)] = cc; sm[lds_slot(p)] = a; }
            }
        }
        __syncthreads();
    }
    #pragma unroll
    for (int r = 0; r < 4; ++r) key[r] = sm[lds_slot(4 * t + r)];

    for (int j = 128; j >= 4; j >>= 1) {       // cross-lane via shfl_xor
        int d = j >> 2;
        #pragma unroll
        for (int r = 0; r < 4; ++r) {
            int el = 4 * t + r;
            u64 mine = key[r];
            u64 part = __shfl_xor(mine, d, 64);
            bool lower = ((el & j) == 0);
            u64 mn = (mine < part) ? mine : part;
            u64 mx = (mine < part) ? part : mine;
            key[r] = lower ? mn : mx;
        }
    }
    for (int j = 2; j >= 1; j >>= 1) {         // j in {2,1}: in-thread
        #pragma unroll
        for (int r = 0; r < 4; ++r) {
            int pr = r | j;
            if (((r & j) == 0) && pr < 4) {
                u64 a = key[r], cc = key[pr];
                if (a > cc) { key[r] = cc; key[pr] = a; }
            }
        }
    }

    #pragma unroll
    for (int r = 0; r < 4; ++r) {
        int e = ebase + 4 * t + r;
        u32 orig = (u32)key[r];
        const float* bp = in + ((size_t)b * NMS_N + orig) * 5;
        float x = bp[1], y = bp[2], w = bp[3], h = bp[4];
        float ws_ = floorf(w * 0.5f);
        float hs_ = floorf(h * 0.5f);
        float X1 = x - ws_, Y1 = y - hs_, X2 = x + ws_, Y2 = y + hs_;
        size_t g = (size_t)b * NMS_N + e;
        sortedIdx[g] = orig;
        crn[g] = make_float4(X1, Y1, X2, Y2);
        ha[g] = 0.5f * ((X2 - X1) * (Y2 - Y1));   // exact: area is a small int
    }
}

// ---------------------------------------------------------------------------
// K2: suppression bitmask, ballot orientation, equal-work trapezoid grid.
// Diagonal units (rowblk==2wp, 2wp+1) also write the dense diag array
// diagw2[b][wp][r] = words (2wp,2wp+1) of row 128*wp+r — fully computed
// words (all bits valid IoU results). Unchanged.
// ---------------------------------------------------------------------------
__global__ __launch_bounds__(256) void nms_mask(
        const float4* __restrict__ crn, const float* __restrict__ ha,
        u64* __restrict__ mask, u64* __restrict__ diagw2) {
    const int b = blockIdx.y;
    const int u = blockIdx.x * 4 + (threadIdx.x >> 6);   // unit id, 0..1055
    const int lane = threadIdx.x & 63;

    int wp = (int)sqrtf((float)u);
    while (wp * (wp + 1) > u) --wp;
    while ((wp + 1) * (wp + 2) <= u) ++wp;
    const int rowblk = u - wp * (wp + 1);                // 0..2*wp+1

    const size_t base = (size_t)b * NMS_N;
    const int c0 = wp * 128 + lane;
    float4 c0c = crn[base + c0];
    float4 c1c = crn[base + c0 + 64];
    float h0 = ha[base + c0];
    float h1 = ha[base + c0 + 64];

    const int rowbase = __builtin_amdgcn_readfirstlane(rowblk * 64);
    const float4* rowc = crn + base + rowbase;
    const float* rowh = ha + base + rowbase;

    u64 w0 = 0, w1 = 0;
    for (int rg = 0; rg < 64; rg += 8) {
        float fx1[8], fy1[8], fx2[8], fy2[8], fha[8];
        #pragma unroll
        for (int q = 0; q < 8; ++q) {                    // uniform -> s_load
            float4 rc = rowc[rg + q];
            fx1[q] = rc.x; fy1[q] = rc.y; fx2[q] = rc.z; fy2[q] = rc.w;
            fha[q] = rowh[rg + q];
        }
        #pragma unroll
        for (int q = 0; q < 8; ++q) {
            float iw0 = fmaxf(fminf(fx2[q], c0c.z) - fmaxf(fx1[q], c0c.x), 0.0f);
            float ih0 = fmaxf(fminf(fy2[q], c0c.w) - fmaxf(fy1[q], c0c.y), 0.0f);
            float in0 = iw0 * ih0;
            bool p0 = in0 > fmaf(-0.5f, in0, fha[q] + h0);

            float iw1 = fmaxf(fminf(fx2[q], c1c.z) - fmaxf(fx1[q], c1c.x), 0.0f);
            float ih1 = fmaxf(fminf(fy2[q], c1c.w) - fmaxf(fy1[q], c1c.y), 0.0f);
            float in1 = iw1 * ih1;
            bool p1 = in1 > fmaf(-0.5f, in1, fha[q] + h1);

            u64 b0 = __ballot(p0);
            u64 b1 = __ballot(p1);
            if (lane == rg + q) { w0 = b0; w1 = b1; }
        }
    }

    ulonglong2 v; v.x = w0; v.y = w1;
    *(ulonglong2*)&mask[(base + rowbase + lane) * NMS_NW + wp * 2] = v;

    if (rowblk == 2 * wp || rowblk == 2 * wp + 1) {      // diagonal unit
        int r = ((rowblk & 1) << 6) + lane;              // row offset in 128-window
        *(ulonglong2*)&diagw2[(((size_t)b * 32 + wp) * 128 + r) * 2] = v;
    }
}

// ---------------------------------------------------------------------------
// K3 v3: register-resident suppression bitmask + 128-row windows.
//   - supp: lane l holds suppressed-mask word l (64 lanes x 64 bits = the
//     full 4096-bit vector). curwin = one readlane, no gather/butterfly.
//   - per kept row: ONE coalesced 512B load (lane l reads word l of the
//     row's mask) OR'd into supp. Loads issued 4-wide from the window's
//     kept-bitmap -> ~1 latency per window instead of per row.
//   - windows are 128 rows (diagw2 stores the full 128x128 diagonal block),
//     so only 32 serial memory round-trips instead of 64.
//   Garbage note: mask words w < 2*(row/128) are never written by K2; they
//   get OR'd into supp words of windows already passed -> never read.
//   Within-window order: lo 64 rows fully processed before hi 64; a kept lo
//   row suppresses hi rows via word 2wp+1; hi rows never affect lo rows.
// ---------------------------------------------------------------------------
__global__ __launch_bounds__(64, 1) void nms_scan(
        const float* __restrict__ in, const u64* __restrict__ mask,
        const u64* __restrict__ diagw2, const u32* __restrict__ sortedIdx,
        float* __restrict__ outp) {
    const int b = blockIdx.x, lane = threadIdx.x;
    const u64* M = mask + (size_t)b * NMS_N * NMS_NW;
    const u64* D = diagw2 + (size_t)b * 32 * 128 * 2;

    __shared__ int kept[ROIS];
    for (int r = lane; r < ROIS; r += 64) kept[r] = 0;   // safety fallback

    int count = 0;
    u64 supp = 0;        // lane l owns suppressed word l (cols 64l..64l+63)

    // diag for window 0: rows 0..127, words 0,1. Hi rows only need word 1
    // (word 0 targets lo rows, which are already decided by then).
    u64 dLo0, dLo1, dHi1;
    {
        ulonglong2 tl = *(const ulonglong2*)&D[(size_t)lane * 2];
        dLo0 = tl.x; dLo1 = tl.y;
        dHi1 = D[(size_t)(64 + lane) * 2 + 1];
    }

    for (int Wp = 0; Wp < 32 && count < ROIS; ++Wp) {
        // prefetch next window's diagonal block
        u64 nLo0 = 0, nLo1 = 0, nHi1 = 0;
        if (Wp + 1 < 32) {
            const u64* Dn = D + (size_t)(Wp + 1) * 128 * 2;
            ulonglong2 tl = *(const ulonglong2*)&Dn[(size_t)lane * 2];
            nLo0 = tl.x; nLo1 = tl.y;
            nHi1 = Dn[(size_t)(64 + lane) * 2 + 1];
        }

        u64 availLo = ~rdlane_u64(supp, 2 * Wp);
        u64 availHi = ~rdlane_u64(supp, 2 * Wp + 1);
        u64 kbLo = 0, kbHi = 0;

        // ---- serial scalar ctz-skip scan, lo half then hi half ----
        while (availLo != 0 && count < ROIS) {
            int r = __builtin_ctzll(availLo);
            u64 d0 = rdlane_u64(dLo0, r);
            u64 d1 = rdlane_u64(dLo1, r);
            if (lane == 0) kept[count] = Wp * 128 + r;
            ++count;
            kbLo |= (1ULL << r);
            availLo &= ~(d0 | (1ULL << r));
            availHi &= ~d1;
        }
        while (availHi != 0 && count < ROIS) {
            int r = __builtin_ctzll(availHi);
            u64 d1 = rdlane_u64(dHi1, r);
            if (lane == 0) kept[count] = Wp * 128 + 64 + r;
            ++count;
            kbHi |= (1ULL << r);
            availHi &= ~(d1 | (1ULL << r));
        }

        if (count >= ROIS) break;              // no future windows -> no update

        // ---- OR kept rows' full mask rows into supp, 4 loads in flight ----
        u64 acc = 0;
        #pragma unroll 1
        for (int half = 0; half < 2; ++half) {
            u64 kb = half ? kbHi : kbLo;
            const int rbase = Wp * 128 + half * 64;
            while (kb != 0) {
                int r0 = __builtin_ctzll(kb);  u64 k1 = kb & (kb - 1);
                int r1 = k1 ? __builtin_ctzll(k1) : r0;  u64 k2 = k1 ? (k1 & (k1 - 1)) : 0;
                int r2 = k2 ? __builtin_ctzll(k2) : r0;  u64 k3 = k2 ? (k2 & (k2 - 1)) : 0;
                int r3 = k3 ? __builtin_ctzll(k3) : r0;  kb = k3 ? (k3 & (k3 - 1)) : 0;
                u64 v0 = M[(size_t)(rbase + r0) * NMS_NW + lane];
                u64 v1 = M[(size_t)(rbase + r1) * NMS_NW + lane];
                u64 v2 = M[(size_t)(rbase + r2) * NMS_NW + lane];
                u64 v3 = M[(size_t)(rbase + r3) * NMS_NW + lane];
                acc |= (v0 | v1) | (v2 | v3);  // duplicates OK (OR idempotent)
            }
        }
        supp |= acc;

        dLo0 = nLo0; dLo1 = nLo1; dHi1 = nHi1;
    }

    __syncthreads();
    for (int r = lane; r < ROIS; r += 64) {
        int pos = kept[r];
        int orig = (int)sortedIdx[(size_t)b * NMS_N + pos];
        const float* bp = in + ((size_t)b * NMS_N + orig) * 5;
        float4 o = make_float4(bp[1], bp[2], bp[3], bp[4]);
        ((float4*)outp)[(size_t)b * ROIS + r] = o;
    }
}

extern "C" void kernel_launch(void* const* d_in, const int* in_sizes, int n_in,
                              void* d_out, int out_size, void* d_ws, size_t ws_size,
                              hipStream_t stream) {
    const float* in = (const float*)d_in[0];
    float* out = (float*)d_out;
    char* ws = (char*)d_ws;

    u64* mask = (u64*)ws;                                          // 16 MB
    size_t off = (size_t)NMS_B * NMS_N * NMS_NW * sizeof(u64);
    u32* sortedIdx = (u32*)(ws + off); off += (size_t)NMS_B * NMS_N * 4;
    float4* crn = (float4*)(ws + off); off += (size_t)NMS_B * NMS_N * 16;
    float* ha = (float*)(ws + off);    off += (size_t)NMS_B * NMS_N * 4;
    u64* keyb = (u64*)(ws + off);      off += (size_t)NMS_B * NMS_N * 8;
    u64* diagw2 = (u64*)(ws + off);    off += (size_t)NMS_B * 32 * 128 * 2 * 8;

    nms_sort_local<<<dim3(2, NMS_B), 512, 0, stream>>>(in, keyb);
    nms_sort_merge<<<dim3(2, NMS_B), 512, 0, stream>>>(in, keyb, sortedIdx, crn, ha);
    nms_mask<<<dim3(264, NMS_B), 256, 0, stream>>>(crn, ha, mask, diagw2);
    nms_scan<<<NMS_B, 64, 0, stream>>>(in, mask, diagw2, sortedIdx, out);
}

// Round 2
// 154.021 us; speedup vs baseline: 1.0396x; 1.0396x over previous
//
#include <hip/hip_runtime.h>
#include <stdint.h>

#pragma clang fp contract(off)

#define NMS_B 8
#define NMS_N 4096
#define NMS_NW 64       // 64-bit words per suppression row
#define ROIS 256

typedef unsigned long long u64;
typedef unsigned int u32;

__device__ __forceinline__ u64 rdlane_u64(u64 v, int l) {
    u32 lo = (u32)__builtin_amdgcn_readlane((int)(u32)v, l);
    u32 hi = (u32)__builtin_amdgcn_readlane((int)(u32)(v >> 32), l);
    return ((u64)hi << 32) | lo;
}
__device__ __forceinline__ u64 rdfirst_u64(u64 v) {
    u32 lo = (u32)__builtin_amdgcn_readfirstlane((int)(u32)v);
    u32 hi = (u32)__builtin_amdgcn_readfirstlane((int)(u32)(v >> 32));
    return ((u64)hi << 32) | lo;
}
__device__ __forceinline__ int lds_slot(int e) { return e + (e >> 2); }  // 4-way max bank aliasing

// ---------------------------------------------------------------------------
// K1a: local bitonic sort of 2048-element chunks (2 chunks/batch, 16 blocks,
// 512 thr x 4 elems). key = (~score_bits)<<32 | GLOBAL idx; direction bits
// use global e, so the result is bit-identical to the monolithic bitonic
// after its k=2048 stage. (unchanged)
// ---------------------------------------------------------------------------
__global__ __launch_bounds__(512) void nms_sort_local(
        const float* __restrict__ in, u64* __restrict__ keyb) {
    __shared__ u64 sm[2560];                   // slot(2047)=2558, 20.5 KB
    const int b = blockIdx.y, c = blockIdx.x, t = threadIdx.x;
    const int ebase = c * 2048;
    u64 key[4];

    #pragma unroll
    for (int r = 0; r < 4; ++r) {
        int e = ebase + 4 * t + r;
        float s = in[((size_t)b * NMS_N + e) * 5];
        key[r] = ((u64)(~__float_as_uint(s)) << 32) | (u32)e;
    }

    for (int k = 2; k <= 2048; k <<= 1) {
        int j = k >> 1;
        if (j >= 256) {                        // j = 1024,512,256 via LDS
            #pragma unroll
            for (int r = 0; r < 4; ++r) sm[lds_slot(4 * t + r)] = key[r];
            __syncthreads();
            for (; j >= 256; j >>= 1) {
                for (int el = t; el < 2048; el += 512) {
                    int p = el ^ j;
                    if (p > el) {
                        u64 a = sm[lds_slot(el)], cc = sm[lds_slot(p)];
                        bool up = (((ebase + el) & k) == 0);
                        if ((a > cc) == up) { sm[lds_slot(el)] = cc; sm[lds_slot(p)] = a; }
                    }
                }
                __syncthreads();
            }
            #pragma unroll
            for (int r = 0; r < 4; ++r) key[r] = sm[lds_slot(4 * t + r)];
        }
        for (; j >= 4; j >>= 1) {              // cross-lane via shfl_xor
            int d = j >> 2;
            #pragma unroll
            for (int r = 0; r < 4; ++r) {
                int e = ebase + 4 * t + r;
                u64 mine = key[r];
                u64 part = __shfl_xor(mine, d, 64);
                bool up = ((e & k) == 0);
                bool lower = ((e & j) == 0);
                u64 mn = (mine < part) ? mine : part;
                u64 mx = (mine < part) ? part : mine;
                key[r] = (up == lower) ? mn : mx;
            }
        }
        for (; j >= 1; j >>= 1) {              // j in {2,1}: in-thread
            #pragma unroll
            for (int r = 0; r < 4; ++r) {
                int pr = r | j;
                if (((r & j) == 0) && pr < 4) {
                    int e = ebase + 4 * t + r;
                    bool up = ((e & k) == 0);
                    u64 a = key[r], cc = key[pr];
                    if ((a > cc) == up) { key[r] = cc; key[pr] = a; }
                }
            }
        }
    }

    #pragma unroll
    for (int r = 0; r < 4; ++r)
        keyb[(size_t)b * NMS_N + ebase + 4 * t + r] = key[r];
}

// ---------------------------------------------------------------------------
// K1b: merge stage k=4096 at 2x block parallelism (all-ascending at k=4096,
// j=2048 substage computed redundantly from read-only keyb). 16 blocks x
// 512 thr, 20.5 KB LDS. Bit-identical network. Epilogue: sorted idx +
// corners (floor(w/2) per reference) + HALF-areas (exact). (unchanged)
// ---------------------------------------------------------------------------
__global__ __launch_bounds__(512) void nms_sort_merge(
        const float* __restrict__ in, const u64* __restrict__ keyb,
        u32* __restrict__ sortedIdx, float4* __restrict__ crn,
        float* __restrict__ ha) {
    __shared__ u64 sm[2560];                   // slot(2047)=2558, 20.5 KB
    const int b = blockIdx.y, c = blockIdx.x, t = threadIdx.x;
    const int ebase = c * 2048;
    u64 key[4];

    #pragma unroll
    for (int r = 0; r < 4; ++r) {
        int el = 4 * t + r;
        u64 mine = keyb[(size_t)b * NMS_N + ebase + el];
        u64 part = keyb[(size_t)b * NMS_N + (ebase ^ 2048) + el];
        u64 mn = mine < part ? mine : part;
        u64 mx = mine < part ? part : mine;
        key[r] = (c == 0) ? mn : mx;
    }

    #pragma unroll
    for (int r = 0; r < 4; ++r) sm[lds_slot(4 * t + r)] = key[r];
    __syncthreads();
    for (int j = 1024; j >= 256; j >>= 1) {
        for (int el = t; el < 2048; el += 512) {
            int p = el ^ j;
            if (p > el) {
                u64 a = sm[lds_slot(el)], cc = sm[lds_slot(p)];
                if (a > cc) { sm[lds_slot(el)] = cc; sm[lds_slot(p)] = a; }
            }
        }
        __syncthreads();
    }
    #pragma unroll
    for (int r = 0; r < 4; ++r) key[r] = sm[lds_slot(4 * t + r)];

    for (int j = 128; j >= 4; j >>= 1) {       // cross-lane via shfl_xor
        int d = j >> 2;
        #pragma unroll
        for (int r = 0; r < 4; ++r) {
            int el = 4 * t + r;
            u64 mine = key[r];
            u64 part = __shfl_xor(mine, d, 64);
            bool lower = ((el & j) == 0);
            u64 mn = (mine < part) ? mine : part;
            u64 mx = (mine < part) ? part : mine;
            key[r] = lower ? mn : mx;
        }
    }
    for (int j = 2; j >= 1; j >>= 1) {         // j in {2,1}: in-thread
        #pragma unroll
        for (int r = 0; r < 4; ++r) {
            int pr = r | j;
            if (((r & j) == 0) && pr < 4) {
                u64 a = key[r], cc = key[pr];
                if (a > cc) { key[r] = cc; key[pr] = a; }
            }
        }
    }

    #pragma unroll
    for (int r = 0; r < 4; ++r) {
        int e = ebase + 4 * t + r;
        u32 orig = (u32)key[r];
        const float* bp = in + ((size_t)b * NMS_N + orig) * 5;
        float x = bp[1], y = bp[2], w = bp[3], h = bp[4];
        float ws_ = floorf(w * 0.5f);
        float hs_ = floorf(h * 0.5f);
        float X1 = x - ws_, Y1 = y - hs_, X2 = x + ws_, Y2 = y + hs_;
        size_t g = (size_t)b * NMS_N + e;
        sortedIdx[g] = orig;
        crn[g] = make_float4(X1, Y1, X2, Y2);
        ha[g] = 0.5f * ((X2 - X1) * (Y2 - Y1));   // exact: area is a small int
    }
}

// ---------------------------------------------------------------------------
// K2: suppression bitmask, ballot orientation, equal-work trapezoid grid.
// Diagonal units also write the dense diag array diagw2. (unchanged)
// ---------------------------------------------------------------------------
__global__ __launch_bounds__(256) void nms_mask(
        const float4* __restrict__ crn, const float* __restrict__ ha,
        u64* __restrict__ mask, u64* __restrict__ diagw2) {
    const int b = blockIdx.y;
    const int u = blockIdx.x * 4 + (threadIdx.x >> 6);   // unit id, 0..1055
    const int lane = threadIdx.x & 63;

    int wp = (int)sqrtf((float)u);
    while (wp * (wp + 1) > u) --wp;
    while ((wp + 1) * (wp + 2) <= u) ++wp;
    const int rowblk = u - wp * (wp + 1);                // 0..2*wp+1

    const size_t base = (size_t)b * NMS_N;
    const int c0 = wp * 128 + lane;
    float4 c0c = crn[base + c0];
    float4 c1c = crn[base + c0 + 64];
    float h0 = ha[base + c0];
    float h1 = ha[base + c0 + 64];

    const int rowbase = __builtin_amdgcn_readfirstlane(rowblk * 64);
    const float4* rowc = crn + base + rowbase;
    const float* rowh = ha + base + rowbase;

    u64 w0 = 0, w1 = 0;
    for (int rg = 0; rg < 64; rg += 8) {
        float fx1[8], fy1[8], fx2[8], fy2[8], fha[8];
        #pragma unroll
        for (int q = 0; q < 8; ++q) {                    // uniform -> s_load
            float4 rc = rowc[rg + q];
            fx1[q] = rc.x; fy1[q] = rc.y; fx2[q] = rc.z; fy2[q] = rc.w;
            fha[q] = rowh[rg + q];
        }
        #pragma unroll
        for (int q = 0; q < 8; ++q) {
            float iw0 = fmaxf(fminf(fx2[q], c0c.z) - fmaxf(fx1[q], c0c.x), 0.0f);
            float ih0 = fmaxf(fminf(fy2[q], c0c.w) - fmaxf(fy1[q], c0c.y), 0.0f);
            float in0 = iw0 * ih0;
            bool p0 = in0 > fmaf(-0.5f, in0, fha[q] + h0);

            float iw1 = fmaxf(fminf(fx2[q], c1c.z) - fmaxf(fx1[q], c1c.x), 0.0f);
            float ih1 = fmaxf(fminf(fy2[q], c1c.w) - fmaxf(fy1[q], c1c.y), 0.0f);
            float in1 = iw1 * ih1;
            bool p1 = in1 > fmaf(-0.5f, in1, fha[q] + h1);

            u64 b0 = __ballot(p0);
            u64 b1 = __ballot(p1);
            if (lane == rg + q) { w0 = b0; w1 = b1; }
        }
    }

    ulonglong2 v; v.x = w0; v.y = w1;
    *(ulonglong2*)&mask[(base + rowbase + lane) * NMS_NW + wp * 2] = v;

    if (rowblk == 2 * wp || rowblk == 2 * wp + 1) {      // diagonal unit
        int r = ((rowblk & 1) << 6) + lane;              // row offset in 128-window
        *(ulonglong2*)&diagw2[(((size_t)b * 32 + wp) * 128 + r) * 2] = v;
    }
}

// ---------------------------------------------------------------------------
// K3 v4: register-resident supp + 128-row windows + ONE round-trip per
// window. v3's regression: the 4-wide load loop consumed acc in the same
// iteration -> s_waitcnt vmcnt(0) per group -> ~64 dependent round-trips.
// v4: scan collects kbLo/kbHi (register-only), then up to 32 row-loads go
// into DISTINCT unrolled VGPR slots (zero-init, uniform-branch-guarded, no
// use between loads) -> single vmcnt wait per window, all loads in flight.
// Semantics identical to v3 (OR is idempotent/order-free). Garbage-word
// note unchanged: stale mask words only land in already-passed supp words.
// ---------------------------------------------------------------------------
__global__ __launch_bounds__(64, 1) void nms_scan(
        const float* __restrict__ in, const u64* __restrict__ mask,
        const u64* __restrict__ diagw2, const u32* __restrict__ sortedIdx,
        float* __restrict__ outp) {
    const int b = blockIdx.x, lane = threadIdx.x;
    const u64* M = mask + (size_t)b * NMS_N * NMS_NW;
    const u64* D = diagw2 + (size_t)b * 32 * 128 * 2;

    __shared__ int kept[ROIS];
    for (int r = lane; r < ROIS; r += 64) kept[r] = 0;   // safety fallback

    int count = 0;
    u64 supp = 0;        // lane l owns suppressed word l (cols 64l..64l+63)

    // diag for window 0: rows 0..127, words 0,1. Hi rows only need word 1.
    u64 dLo0, dLo1, dHi1;
    {
        ulonglong2 tl = *(const ulonglong2*)&D[(size_t)lane * 2];
        dLo0 = tl.x; dLo1 = tl.y;
        dHi1 = D[(size_t)(64 + lane) * 2 + 1];
    }

    for (int Wp = 0; Wp < 32 && count < ROIS; ++Wp) {
        // prefetch next window's diagonal block (in flight during scan)
        u64 nLo0 = 0, nLo1 = 0, nHi1 = 0;
        if (Wp + 1 < 32) {
            const u64* Dn = D + (size_t)(Wp + 1) * 128 * 2;
            ulonglong2 tl = *(const ulonglong2*)&Dn[(size_t)lane * 2];
            nLo0 = tl.x; nLo1 = tl.y;
            nHi1 = Dn[(size_t)(64 + lane) * 2 + 1];
        }

        u64 availLo = ~rdlane_u64(supp, 2 * Wp);
        u64 availHi = ~rdlane_u64(supp, 2 * Wp + 1);
        u64 kbLo = 0, kbHi = 0;

        // ---- serial scalar ctz-skip scan, register-only ----
        while (availLo != 0 && count < ROIS) {
            int r = __builtin_ctzll(availLo);
            u64 d0 = rdlane_u64(dLo0, r);
            u64 d1 = rdlane_u64(dLo1, r);
            if (lane == 0) kept[count] = Wp * 128 + r;
            ++count;
            kbLo |= (1ULL << r);
            availLo &= ~(d0 | (1ULL << r));
            availHi &= ~d1;
        }
        while (availHi != 0 && count < ROIS) {
            int r = __builtin_ctzll(availHi);
            u64 d1 = rdlane_u64(dHi1, r);
            if (lane == 0) kept[count] = Wp * 128 + 64 + r;
            ++count;
            kbHi |= (1ULL << r);
            availHi &= ~(d1 | (1ULL << r));
        }

        if (count >= ROIS) break;              // no future windows -> no update

        // ---- batched OR of kept rows' mask rows: 32 loads in flight ----
        {
            u64 kb0 = kbLo, kb1 = kbHi;
            const int rbase = Wp * 128;
            while ((kb0 | kb1) != 0) {
                u64 vv[32];
                #pragma unroll
                for (int i = 0; i < 32; ++i) vv[i] = 0;
                #pragma unroll
                for (int i = 0; i < 32; ++i) {
                    if ((kb0 | kb1) != 0) {    // uniform branch; no acc use
                        int r;
                        if (kb0 != 0) { r = __builtin_ctzll(kb0); kb0 &= kb0 - 1; }
                        else          { r = 64 + __builtin_ctzll(kb1); kb1 &= kb1 - 1; }
                        vv[i] = M[(size_t)(rbase + r) * NMS_NW + lane];
                    }
                }
                u64 acc = 0;                   // single waitcnt lands here
                #pragma unroll
                for (int i = 0; i < 32; ++i) acc |= vv[i];
                supp |= acc;
            }
        }

        dLo0 = nLo0; dLo1 = nLo1; dHi1 = nHi1;
    }

    __syncthreads();
    for (int r = lane; r < ROIS; r += 64) {
        int pos = kept[r];
        int orig = (int)sortedIdx[(size_t)b * NMS_N + pos];
        const float* bp = in + ((size_t)b * NMS_N + orig) * 5;
        float4 o = make_float4(bp[1], bp[2], bp[3], bp[4]);
        ((float4*)outp)[(size_t)b * ROIS + r] = o;
    }
}

extern "C" void kernel_launch(void* const* d_in, const int* in_sizes, int n_in,
                              void* d_out, int out_size, void* d_ws, size_t ws_size,
                              hipStream_t stream) {
    const float* in = (const float*)d_in[0];
    float* out = (float*)d_out;
    char* ws = (char*)d_ws;

    u64* mask = (u64*)ws;                                          // 16 MB
    size_t off = (size_t)NMS_B * NMS_N * NMS_NW * sizeof(u64);
    u32* sortedIdx = (u32*)(ws + off); off += (size_t)NMS_B * NMS_N * 4;
    float4* crn = (float4*)(ws + off); off += (size_t)NMS_B * NMS_N * 16;
    float* ha = (float*)(ws + off);    off += (size_t)NMS_B * NMS_N * 4;
    u64* keyb = (u64*)(ws + off);      off += (size_t)NMS_B * NMS_N * 8;
    u64* diagw2 = (u64*)(ws + off);    off += (size_t)NMS_B * 32 * 128 * 2 * 8;

    nms_sort_local<<<dim3(2, NMS_B), 512, 0, stream>>>(in, keyb);
    nms_sort_merge<<<dim3(2, NMS_B), 512, 0, stream>>>(in, keyb, sortedIdx, crn, ha);
    nms_mask<<<dim3(264, NMS_B), 256, 0, stream>>>(crn, ha, mask, diagw2);
    nms_scan<<<NMS_B, 64, 0, stream>>>(in, mask, diagw2, sortedIdx, out);
}